// Round 12
// baseline (182.682 us; speedup 1.0000x reference)
//
#include <hip/hip_runtime.h>
#include <stdint.h>

#define BB 4
#define TT 512
#define NN 4      // heads-inner
#define HH 8      // H
#define DD 64     // D
#define EE 256    // N*D
#define ROWS 2048 // NN*HH*DD floats per (b,t)
#define UPAD 36   // padded u-count (U=35)
#define UH 18     // u rows per block (u-split)
#define USAMP 35  // compile-time sample count (flash path gated on U==35)
#define NCH 8     // K/V chunks
#define CH 64     // rows per chunk

// ---------------- flash-path kernels ----------------

// Fused M-score + vmean partials (R8-proven).
__global__ __launch_bounds__(256)
void m2_kernel(const float* __restrict__ q, const float* __restrict__ k,
               const float* __restrict__ v, const int* __restrict__ idx,
               float* __restrict__ M, float* __restrict__ vpart) {
    if (blockIdx.x >= 2048) {
        int blk = blockIdx.x - 2048;
        int chunk = blk & 7, bh = blk >> 3;
        int b = bh >> 3, h = bh & 7;
        int e = threadIdx.x;
        int n = e >> 6, d = e & 63;
        size_t base = (size_t)b * TT * ROWS + (size_t)(n * HH + h) * DD + d;
        float acc = 0.f;
        int t0 = chunk * 64;
        for (int t = t0; t < t0 + 64; ++t)
            acc += v[base + (size_t)t * ROWS];
        vpart[blk * EE + e] = acc;
        return;
    }
    __shared__ float S[USAMP][33];
    __shared__ float Dh[8][36];
    int i = blockIdx.x;
    int xcd = i & 7;
    int b = xcd >> 1;
    int t = ((i >> 3) << 1) | (xcd & 1);
    int tid = threadIdx.x;
    int wave = tid >> 6, l = tid & 63;
    int h = (tid >> 3) & 7;

    const float* qr = q + ((size_t)(b * TT + t)) * ROWS + tid * 8;
    float4 qa = *(const float4*)qr;
    float4 qb = *(const float4*)(qr + 4);

    const int* irow = idx + t * USAMP;
    #pragma unroll
    for (int s = 0; s < USAMP; ++s) {
        int kt = __builtin_amdgcn_readfirstlane(irow[s]) & (TT - 1);
        const float* kr = k + ((size_t)(b * TT + kt)) * ROWS + tid * 8;
        float4 ka = *(const float4*)kr;
        float4 kb = *(const float4*)(kr + 4);
        float p = qa.x * ka.x + qa.y * ka.y + qa.z * ka.z + qa.w * ka.w
                + qb.x * kb.x + qb.y * kb.y + qb.z * kb.z + qb.w * kb.w;
        p += __shfl_xor(p, 1, 64);
        p += __shfl_xor(p, 2, 64);
        p += __shfl_xor(p, 4, 64);
        if ((l & 7) == 0) S[s][wave * 8 + h] = p;
    }
    __syncthreads();
    for (int j = tid; j < 8 * USAMP; j += 256) {
        int hh = j / USAMP, s = j - hh * USAMP;
        Dh[hh][s] = S[s][hh] + S[s][8 + hh] + S[s][16 + hh] + S[s][24 + hh];
    }
    __syncthreads();
    if (tid < 8) {
        float mx = -3.4e38f, sm = 0.f;
        #pragma unroll
        for (int s = 0; s < USAMP; ++s) {
            float d = Dh[tid][s];
            mx = fmaxf(mx, d);
            sm += d;
        }
        M[(((b << 3) + tid) << 9) + t] = mx - sm * (1.0f / TT);
    }
}

// exact top-k via rank + fused vmean final reduce. Grid: 32 x 512.
__global__ void topk_kernel(const float* __restrict__ M,
                            int* __restrict__ Mtop,
                            const float* __restrict__ vpart,
                            float* __restrict__ vmean, int U) {
    __shared__ float sM[TT];
    int bh = blockIdx.x;
    int t = threadIdx.x;
    sM[t] = M[bh * TT + t];
    if (t < 64) Mtop[bh * 64 + t] = 0;
    if (t < EE) {
        float acc = 0.f;
        #pragma unroll
        for (int c = 0; c < 8; ++c)
            acc += vpart[(bh * 8 + c) * EE + t];
        vmean[bh * EE + t] = acc * (1.0f / TT);
    }
    __syncthreads();
    float mv = sM[t];
    int rank = 0;
    for (int i = 0; i < TT; ++i) {
        float o = sM[i];
        rank += (o > mv) || (o == mv && i < t);
    }
    if (rank < U) Mtop[bh * 64 + rank] = t;
}

// Fused flash-chunked attention + vmean broadcast fill.
// R10 chunk shape (CH=64/NCH=8) + u-split: block = (bh, ch, uhalf), 18 u each.
// LDS 48 KB, 512 attn blocks -> 2 blocks/CU co-resident (staging of one block
// overlaps compute of the other). QK t-tile strided (conflict-free, R9-proven);
// PV register-lean R8 form with o[3].
// Blocks 0..511: attn. Blocks 512..767: fill out with vmean.
__global__ __launch_bounds__(256)
void attn_fill(const float* __restrict__ q, const float* __restrict__ k,
               const float* __restrict__ v, const int* __restrict__ Mtop,
               const float* __restrict__ vmean, float* __restrict__ out,
               float* __restrict__ Opart, float* __restrict__ ml, int U) {
    __shared__ float qs[UH * 132];   //  9.5 KB
    __shared__ float Bs[CH * 132];   // 33.8 KB
    __shared__ float S[UH * 68];     //  4.9 KB

    if (blockIdx.x >= 512) {
        int fb = blockIdx.x - 512;
        size_t i0 = (size_t)fb * 256 + threadIdx.x;
        #pragma unroll
        for (int r = 0; r < 16; ++r) {
            size_t tid4 = (i0 + (size_t)r * 65536) << 2;
            int d = tid4 & 63;
            size_t rest = tid4 >> 6;
            int h = rest & 7;  rest >>= 3;
            int nn = rest & 3; rest >>= 2;
            int b = (int)(rest >> 9);
            int e = (nn << 6) + d;
            int bh = (b << 3) + h;
            float4 val = *(const float4*)(vmean + (size_t)bh * EE + e);
            *(float4*)(out + tid4) = val;
        }
        return;
    }

    int bx = blockIdx.x;
    int bh = bx >> 4;
    int ch = (bx >> 1) & 7;
    int uh = bx & 1;                  // u-half: rows uh*18 .. uh*18+17
    int b = bh >> 3, h = bh & 7;
    int tid = threadIdx.x;
    int wv = tid >> 6, l = tid & 63;
    int ubase = uh * UH;

    float acc[2][4];
    #pragma unroll
    for (int i = 0; i < 2; ++i)
        #pragma unroll
        for (int j = 0; j < 4; ++j) acc[i][j] = 0.f;

    int ug = tid >> 4, tg = tid & 15;   // QK: 9 ug x 16 tg = 144 active, 2 u each

    for (int h2 = 0; h2 < 2; ++h2) {
        int eb = h2 * 128;
        for (int ul = wv; ul < UH; ul += 4) {
            int gu = ubase + ul;
            int uu = (gu < U) ? gu : (U - 1);
            int qt = Mtop[bh * 64 + uu] & (TT - 1);
            size_t rowq = ((size_t)(b * TT + qt)) * ROWS;
            #pragma unroll
            for (int j = 0; j < 2; ++j) {
                int e = eb + l + 64 * j;
                qs[ul * 132 + l + 64 * j] = q[rowq + (size_t)((e >> 6) * HH + h) * DD + (e & 63)];
            }
        }
        for (int r = wv; r < CH; r += 4) {
            size_t rowk = ((size_t)(b * TT + ch * CH + r)) * ROWS;
            #pragma unroll
            for (int j = 0; j < 2; ++j) {
                int e = eb + l + 64 * j;
                Bs[r * 132 + l + 64 * j] = k[rowk + (size_t)((e >> 6) * HH + h) * DD + (e & 63)];
            }
        }
        __syncthreads();
        if (ug < 9) {
            const float4* Qv = (const float4*)qs;
            const float4* Bv = (const float4*)Bs;
            int u0 = ug * 2;
            for (int e4 = 0; e4 < 32; ++e4) {
                float4 k0 = Bv[(tg +  0) * 33 + e4];
                float4 k1 = Bv[(tg + 16) * 33 + e4];
                float4 k2 = Bv[(tg + 32) * 33 + e4];
                float4 k3 = Bv[(tg + 48) * 33 + e4];
                #pragma unroll
                for (int i = 0; i < 2; ++i) {
                    float4 qv = Qv[(u0 + i) * 33 + e4];
                    acc[i][0] += qv.x * k0.x + qv.y * k0.y + qv.z * k0.z + qv.w * k0.w;
                    acc[i][1] += qv.x * k1.x + qv.y * k1.y + qv.z * k1.z + qv.w * k1.w;
                    acc[i][2] += qv.x * k2.x + qv.y * k2.y + qv.z * k2.z + qv.w * k2.w;
                    acc[i][3] += qv.x * k3.x + qv.y * k3.y + qv.z * k3.z + qv.w * k3.w;
                }
            }
        }
        __syncthreads();
    }
    if (ug < 9) {
        int u0 = ug * 2;
        #pragma unroll
        for (int i = 0; i < 2; ++i)
            #pragma unroll
            for (int j = 0; j < 4; ++j)
                S[(u0 + i) * 68 + tg + 16 * j] = acc[i][j] * 0.125f;
    }
    __syncthreads();

    if (tid < UH) {
        float m = -3.4e38f;
        for (int t = 0; t < CH; ++t) m = fmaxf(m, S[tid * 68 + t]);
        float lsum = 0.f;
        for (int t = 0; t < CH; ++t) {
            float p = __expf(S[tid * 68 + t] - m);
            S[tid * 68 + t] = p;
            lsum += p;
        }
        size_t mli = ((size_t)(bh * NCH + ch) * UPAD + ubase + tid) * 2;
        ml[mli] = m;
        ml[mli + 1] = lsum;
    }
    __syncthreads();

    int ugp = tid >> 5, el = tid & 31;  // PV: 6 groups x 3 u = 18; groups 6,7 idle
    int u0p = ugp * 3;
    for (int vh = 0; vh < 2; ++vh) {
        for (int r = wv; r < CH; r += 4) {
            size_t rowv = ((size_t)(b * TT + ch * CH + r)) * ROWS;
            #pragma unroll
            for (int j = 0; j < 2; ++j) {
                int e = vh * 128 + l + 64 * j;
                Bs[r * 132 + l + 64 * j] = v[rowv + (size_t)((e >> 6) * HH + h) * DD + (e & 63)];
            }
        }
        __syncthreads();
        float4 o[3];
        #pragma unroll
        for (int i = 0; i < 3; ++i) o[i] = make_float4(0.f, 0.f, 0.f, 0.f);
        if (u0p < UH) {
            for (int t = 0; t < CH; ++t) {
                float4 v4 = *(const float4*)&Bs[t * 132 + 4 * el];
                #pragma unroll
                for (int i = 0; i < 3; ++i) {
                    int uc = u0p + i; if (uc > UH - 1) uc = UH - 1;
                    float p = S[uc * 68 + t];
                    o[i].x += p * v4.x; o[i].y += p * v4.y;
                    o[i].z += p * v4.z; o[i].w += p * v4.w;
                }
            }
            #pragma unroll
            for (int i = 0; i < 3; ++i) {
                int ul = u0p + i;
                if (ul < UH)
                    *(float4*)&Opart[((size_t)(bh * NCH + ch) * UPAD + ubase + ul) * EE
                                     + vh * 128 + 4 * el] = o[i];
            }
        }
        __syncthreads();
    }
}

// merge chunk partials, write selected rows into out. Grid: 32*U x 64.
__global__ void combine_kernel(const float* __restrict__ Opart,
                               const float* __restrict__ ml,
                               const int* __restrict__ Mtop,
                               float* __restrict__ out, int U) {
    int bx = blockIdx.x;
    int bh = bx / U, ui = bx % U;
    int b = bh >> 3, h = bh & 7;
    int el = threadIdx.x;
    float mc[NCH], lc[NCH];
    float gm = -3.4e38f;
    #pragma unroll
    for (int c = 0; c < NCH; ++c) {
        size_t mli = ((size_t)(bh * NCH + c) * UPAD + ui) * 2;
        mc[c] = ml[mli]; lc[c] = ml[mli + 1];
        gm = fmaxf(gm, mc[c]);
    }
    float L = 0.f;
    float fc[NCH];
    #pragma unroll
    for (int c = 0; c < NCH; ++c) { fc[c] = __expf(mc[c] - gm); L += lc[c] * fc[c]; }
    float inv = 1.0f / L;
    float4 a = make_float4(0.f, 0.f, 0.f, 0.f);
    #pragma unroll
    for (int c = 0; c < NCH; ++c) {
        float4 o = *(const float4*)&Opart[((size_t)(bh * NCH + c) * UPAD + ui) * EE + 4 * el];
        a.x += fc[c] * o.x; a.y += fc[c] * o.y;
        a.z += fc[c] * o.z; a.w += fc[c] * o.w;
    }
    int qt = Mtop[bh * 64 + ui] & (TT - 1);
    int e0 = 4 * el, n = el >> 4;
    size_t ooff = ((size_t)(b * TT + qt)) * ROWS + (size_t)(n * HH + h) * DD + (e0 & 63);
    a.x *= inv; a.y *= inv; a.z *= inv; a.w *= inv;
    *(float4*)(out + ooff) = a;
}

// ---------------- mid-path kernels (ws >= 160 KB only) ----------------

__global__ __launch_bounds__(1024)
void vmean_kernel(const float* __restrict__ v, float* __restrict__ vmean) {
    __shared__ float part[4][EE];
    int bh = blockIdx.x;
    int b = bh >> 3, h = bh & 7;
    int e = threadIdx.x & 255;
    int chunk = threadIdx.x >> 8;
    int n = e >> 6, d = e & 63;
    size_t base = (size_t)b * TT * ROWS + (size_t)(n * HH + h) * DD + d;
    float acc = 0.f;
    int t0 = chunk * 128;
    for (int t = t0; t < t0 + 128; ++t)
        acc += v[base + (size_t)t * ROWS];
    part[chunk][e] = acc;
    __syncthreads();
    if (threadIdx.x < EE)
        vmean[bh * EE + threadIdx.x] =
            (part[0][threadIdx.x] + part[1][threadIdx.x] +
             part[2][threadIdx.x] + part[3][threadIdx.x]) * (1.0f / TT);
}

__global__ void fill_kernel(const float* __restrict__ vmean,
                            float* __restrict__ out) {
    size_t tid4 = ((size_t)blockIdx.x * 256 + threadIdx.x) << 2;
    int d = tid4 & 63;
    size_t rest = tid4 >> 6;
    int h = rest & 7;  rest >>= 3;
    int n = rest & 3;  rest >>= 2;
    int b = (int)(rest >> 9);
    int e = (n << 6) + d;
    int bh = (b << 3) + h;
    float4 val = *(const float4*)(vmean + (size_t)bh * EE + e);
    *(float4*)(out + tid4) = val;
}

__global__ void m_only_kernel(const float* __restrict__ q,
                              const float* __restrict__ k,
                              const int* __restrict__ idx,
                              float* __restrict__ M, int U) {
    int wave = threadIdx.x >> 6, lane = threadIdx.x & 63;
    int r = (blockIdx.x << 2) + wave;
    int t = r & (TT - 1);
    int bh = r >> 9;
    int b = bh >> 3, h = bh & 7;
    int g = lane >> 4, x = lane & 15;
    int n = x >> 2;
    int dbase = (x & 3) << 4;
    size_t colbase = (size_t)(n * HH + h) * DD + dbase;
    size_t qrow = ((size_t)(b * TT + t)) * ROWS + colbase;
    float4 qv0 = *(const float4*)(q + qrow);
    float4 qv1 = *(const float4*)(q + qrow + 4);
    float4 qv2 = *(const float4*)(q + qrow + 8);
    float4 qv3 = *(const float4*)(q + qrow + 12);
    float mx = -3.4e38f, sm = 0.f;
    int NB = (U + 3) >> 2;
    for (int bs = 0; bs < NB; ++bs) {
        int s = (bs << 2) + g;
        int valid = s < U;
        int sc = valid ? s : (U - 1);
        int kt = idx[t * U + sc] & (TT - 1);
        size_t krow = ((size_t)(b * TT + kt)) * ROWS + colbase;
        float4 kv0 = *(const float4*)(k + krow);
        float4 kv1 = *(const float4*)(k + krow + 4);
        float4 kv2 = *(const float4*)(k + krow + 8);
        float4 kv3 = *(const float4*)(k + krow + 12);
        float dot = qv0.x * kv0.x + qv0.y * kv0.y + qv0.z * kv0.z + qv0.w * kv0.w
                  + qv1.x * kv1.x + qv1.y * kv1.y + qv1.z * kv1.z + qv1.w * kv1.w
                  + qv2.x * kv2.x + qv2.y * kv2.y + qv2.z * kv2.z + qv2.w * kv2.w
                  + qv3.x * kv3.x + qv3.y * kv3.y + qv3.z * kv3.z + qv3.w * kv3.w;
        #pragma unroll
        for (int off = 1; off < 16; off <<= 1)
            dot += __shfl_xor(dot, off, 64);
        if (valid) { mx = fmaxf(mx, dot); sm += dot; }
    }
    mx = fmaxf(mx, __shfl_xor(mx, 16, 64));
    mx = fmaxf(mx, __shfl_xor(mx, 32, 64));
    sm += __shfl_xor(sm, 16, 64);
    sm += __shfl_xor(sm, 32, 64);
    if (lane == 0) M[r] = mx - sm * (1.0f / TT);
}

__global__ void topk_only_kernel(const float* __restrict__ M,
                                 int* __restrict__ Mtop, int U) {
    __shared__ float sM[TT];
    int bh = blockIdx.x;
    int t = threadIdx.x;
    sM[t] = M[bh * TT + t];
    if (t < 64) Mtop[bh * 64 + t] = 0;
    __syncthreads();
    float mv = sM[t];
    int rank = 0;
    for (int i = 0; i < TT; ++i) {
        float o = sM[i];
        rank += (o > mv) || (o == mv && i < t);
    }
    if (rank < U) Mtop[bh * 64 + rank] = t;
}

__global__ void update_kernel(const float* __restrict__ q,
                              const float* __restrict__ k,
                              const float* __restrict__ v,
                              const int* __restrict__ Mtop,
                              float* __restrict__ out, int U) {
    __shared__ float qs[EE];
    __shared__ float sc[TT];
    __shared__ float red[256];
    int blk = blockIdx.x;
    int ui = blk % U;
    int bh = blk / U;
    int b = bh >> 3, h = bh & 7;
    int tid = threadIdx.x;
    int qt = Mtop[bh * 64 + ui] & (TT - 1);
    {
        int n = tid >> 6, d = tid & 63;
        qs[tid] = q[((size_t)(b * TT + qt)) * ROWS + (size_t)(n * HH + h) * DD + d];
    }
    __syncthreads();
    #pragma unroll
    for (int rep = 0; rep < 2; ++rep) {
        int t = tid + rep * 256;
        size_t kb = ((size_t)(b * TT + t)) * ROWS + (size_t)h * DD;
        float acc = 0.f;
        #pragma unroll
        for (int n = 0; n < NN; ++n) {
            const float* kn = k + kb + (size_t)n * HH * DD;
            #pragma unroll 4
            for (int d4 = 0; d4 < DD; d4 += 4) {
                float4 kv = *(const float4*)(kn + d4);
                int e = n * 64 + d4;
                acc += qs[e] * kv.x + qs[e + 1] * kv.y + qs[e + 2] * kv.z + qs[e + 3] * kv.w;
            }
        }
        sc[t] = acc * 0.125f;
    }
    __syncthreads();
    red[tid] = fmaxf(sc[tid], sc[tid + 256]);
    __syncthreads();
    for (int s = 128; s > 0; s >>= 1) {
        if (tid < s) red[tid] = fmaxf(red[tid], red[tid + s]);
        __syncthreads();
    }
    float mx = red[0];
    __syncthreads();
    float e0 = __expf(sc[tid] - mx);
    float e1 = __expf(sc[tid + 256] - mx);
    sc[tid] = e0; sc[tid + 256] = e1;
    red[tid] = e0 + e1;
    __syncthreads();
    for (int s = 128; s > 0; s >>= 1) {
        if (tid < s) red[tid] += red[tid + s];
        __syncthreads();
    }
    float inv = 1.0f / red[0];
    __syncthreads();
    {
        int n = tid >> 6, d = tid & 63;
        size_t vb = (size_t)b * TT * ROWS + (size_t)(n * HH + h) * DD + d;
        float acc = 0.f;
        for (int t = 0; t < TT; ++t)
            acc += sc[t] * v[vb + (size_t)t * ROWS];
        out[((size_t)(b * TT + qt)) * ROWS + (size_t)(n * HH + h) * DD + d] = acc * inv;
    }
}

// ---------------- last-resort fallback (no ws): fused, fp32 ----------------
__global__ __launch_bounds__(1024)
void fused_probattn(const float* __restrict__ qp, const float* __restrict__ kp,
                    const float* __restrict__ vp, const int* __restrict__ idx,
                    float* __restrict__ out, int U) {
    __shared__ float vmean[EE];
    __shared__ float M[TT];
    __shared__ float sc[TT];
    __shared__ float qs[EE];
    __shared__ float red[64];
    __shared__ int   Mtop[64];
    const int bh = blockIdx.x;
    const int b = bh >> 3, h = bh & 7;
    const int tid = threadIdx.x;
    const int wave = tid >> 6, lane = tid & 63;
    if (tid < EE) {
        int n = tid >> 6, d = tid & 63;
        size_t base = (size_t)b * TT * ROWS + (size_t)(n * HH + h) * DD + d;
        float acc = 0.f;
        for (int t = 0; t < TT; ++t) acc += vp[base + (size_t)t * ROWS];
        vmean[tid] = acc * (1.0f / TT);
    }
    __syncthreads();
    for (int i = tid; i < TT * EE; i += 1024) {
        int t = i >> 8, e = i & 255;
        int n = e >> 6, d = e & 63;
        out[((size_t)(b * TT + t)) * ROWS + (size_t)(n * HH + h) * DD + d] = vmean[e];
    }
    {
        int e = lane << 2;
        int n = e >> 6, d = e & 63;
        size_t ebase = (size_t)(n * HH + h) * DD + d;
        for (int t = wave; t < TT; t += 16) {
            float4 qv = *(const float4*)(qp + ((size_t)(b * TT + t)) * ROWS + ebase);
            float mx = -3.4e38f, sm = 0.f;
            for (int s = 0; s < U; ++s) {
                int kt = idx[t * U + s] & (TT - 1);
                float4 kv = *(const float4*)(kp + ((size_t)(b * TT + kt)) * ROWS + ebase);
                float dot = qv.x * kv.x + qv.y * kv.y + qv.z * kv.z + qv.w * kv.w;
                #pragma unroll
                for (int off = 32; off; off >>= 1) dot += __shfl_xor(dot, off, 64);
                mx = fmaxf(mx, dot);
                sm += dot;
            }
            if (lane == 0) M[t] = mx - sm * (1.0f / TT);
        }
    }
    __syncthreads();
    if (tid < 64) Mtop[tid] = 0;
    __syncthreads();
    if (tid < TT) {
        float mv = M[tid];
        int rank = 0;
        for (int i = 0; i < TT; ++i) {
            float o = M[i];
            rank += (o > mv) || (o == mv && i < tid);
        }
        if (rank < U) Mtop[rank] = tid;
    }
    __syncthreads();
    for (int ui = 0; ui < U; ++ui) {
        int qt = Mtop[ui];
        if (tid < EE) {
            int n = tid >> 6, d = tid & 63;
            qs[tid] = qp[((size_t)(b * TT + qt)) * ROWS + (size_t)(n * HH + h) * DD + d];
        }
        __syncthreads();
        if (tid < TT) {
            float acc = 0.f;
            size_t kb = ((size_t)(b * TT + tid)) * ROWS + (size_t)h * DD;
            for (int n = 0; n < NN; ++n) {
                const float* kn = kp + kb + (size_t)n * HH * DD;
                for (int d = 0; d < DD; ++d) acc += qs[n * 64 + d] * kn[d];
            }
            sc[tid] = acc * 0.125f;
        }
        __syncthreads();
        float val = (tid < TT) ? sc[tid] : -3.4e38f;
        #pragma unroll
        for (int off = 32; off; off >>= 1) val = fmaxf(val, __shfl_xor(val, off, 64));
        if (lane == 0) red[wave] = val;
        __syncthreads();
        if (tid == 0) {
            float m = red[0];
            for (int w = 1; w < 16; ++w) m = fmaxf(m, red[w]);
            red[32] = m;
        }
        __syncthreads();
        float mx = red[32];
        float ev = 0.f;
        if (tid < TT) { ev = __expf(sc[tid] - mx); sc[tid] = ev; }
        __syncthreads();
        float sv = ev;
        #pragma unroll
        for (int off = 32; off; off >>= 1) sv += __shfl_xor(sv, off, 64);
        if (lane == 0) red[wave] = sv;
        __syncthreads();
        if (tid == 0) {
            float s = 0.f;
            for (int w = 0; w < 16; ++w) s += red[w];
            red[32] = s;
        }
        __syncthreads();
        float inv = 1.0f / red[32];
        if (tid < EE) {
            int n = tid >> 6, d = tid & 63;
            size_t vb = (size_t)b * TT * ROWS + (size_t)(n * HH + h) * DD + d;
            float acc = 0.f;
            for (int t = 0; t < TT; ++t) acc += sc[t] * vp[vb + (size_t)t * ROWS];
            out[((size_t)(b * TT + qt)) * ROWS + (size_t)(n * HH + h) * DD + d] = acc * inv;
        }
        __syncthreads();
    }
}

extern "C" void kernel_launch(void* const* d_in, const int* in_sizes, int n_in,
                              void* d_out, int out_size, void* d_ws, size_t ws_size,
                              hipStream_t stream) {
    const float* q = (const float*)d_in[0];
    const float* k = (const float*)d_in[1];
    const float* v = (const float*)d_in[2];
    const int* idx = (const int*)d_in[3];
    float* out = (float*)d_out;
    int U = in_sizes[3] / TT;        // 35

    // ws layout (bytes) — identical to R10:
    //   M      @ 0        (64 KB)
    //   Mtop   @ 65536    (8 KB)
    //   vmean  @ 98304    (32 KB)
    //   ml     @ 131072   (73.7 KB)  [flash only]
    //   Opart  @ 204800   (9.44 MB)  [flash only]
    //   vpart  @ 204800   (256 KB)   [flash only; aliases Opart — disjoint lifetime]
    const size_t NEED_FLASH = 204800 + (size_t)32 * NCH * UPAD * EE * 4 + 1024;
    const size_t NEED_MID = 160 * 1024;
    char* ws = (char*)d_ws;
    float* M     = (float*)(ws);
    int*   Mtop  = (int*)  (ws + 65536);
    float* vmean = (float*)(ws + 98304);
    float* ml    = (float*)(ws + 131072);
    float* Opart = (float*)(ws + 204800);
    float* vpart = (float*)(ws + 204800);

    if (ws_size >= NEED_FLASH && U == USAMP) {
        m2_kernel<<<2048 + 256, 256, 0, stream>>>(q, k, v, idx, M, vpart);
        topk_kernel<<<BB * HH, TT, 0, stream>>>(M, Mtop, vpart, vmean, U);
        attn_fill<<<512 + 256, 256, 0, stream>>>(q, k, v, Mtop, vmean, out, Opart, ml, U);
        combine_kernel<<<BB * HH * U, 64, 0, stream>>>(Opart, ml, Mtop, out, U);
    } else if (ws_size >= NEED_MID) {
        vmean_kernel<<<BB * HH, 1024, 0, stream>>>(v, vmean);
        fill_kernel<<<4096, 256, 0, stream>>>(vmean, out);
        m_only_kernel<<<BB * HH * TT / 4, 256, 0, stream>>>(q, k, idx, M, U);
        topk_only_kernel<<<BB * HH, TT, 0, stream>>>(M, Mtop, U);
        update_kernel<<<BB * HH * U, 256, 0, stream>>>(q, k, v, Mtop, out, U);
    } else {
        fused_probattn<<<BB * HH, 1024, 0, stream>>>(q, k, v, idx, out, U);
    }
}

// Round 13
// 156.625 us; speedup vs baseline: 1.1664x; 1.1664x over previous
//
#include <hip/hip_runtime.h>
#include <stdint.h>

#define BB 4
#define TT 512
#define NN 4      // heads-inner
#define HH 8      // H
#define DD 64     // D
#define EE 256    // N*D
#define ROWS 2048 // NN*HH*DD floats per (b,t)
#define UPAD 36   // padded u-count (U=35)
#define USAMP 35  // compile-time sample count (flash path gated on U==35)
#define NCH 8     // K/V chunks
#define CH 64     // rows per chunk

// ---------------- flash-path kernels ----------------

// Fused M-score + vmean partials (R8-proven).
__global__ __launch_bounds__(256)
void m2_kernel(const float* __restrict__ q, const float* __restrict__ k,
               const float* __restrict__ v, const int* __restrict__ idx,
               float* __restrict__ M, float* __restrict__ vpart) {
    if (blockIdx.x >= 2048) {
        int blk = blockIdx.x - 2048;
        int chunk = blk & 7, bh = blk >> 3;
        int b = bh >> 3, h = bh & 7;
        int e = threadIdx.x;
        int n = e >> 6, d = e & 63;
        size_t base = (size_t)b * TT * ROWS + (size_t)(n * HH + h) * DD + d;
        float acc = 0.f;
        int t0 = chunk * 64;
        for (int t = t0; t < t0 + 64; ++t)
            acc += v[base + (size_t)t * ROWS];
        vpart[blk * EE + e] = acc;
        return;
    }
    __shared__ float S[USAMP][33];
    __shared__ float Dh[8][36];
    int i = blockIdx.x;
    int xcd = i & 7;
    int b = xcd >> 1;
    int t = ((i >> 3) << 1) | (xcd & 1);
    int tid = threadIdx.x;
    int wave = tid >> 6, l = tid & 63;
    int h = (tid >> 3) & 7;

    const float* qr = q + ((size_t)(b * TT + t)) * ROWS + tid * 8;
    float4 qa = *(const float4*)qr;
    float4 qb = *(const float4*)(qr + 4);

    const int* irow = idx + t * USAMP;
    #pragma unroll
    for (int s = 0; s < USAMP; ++s) {
        int kt = __builtin_amdgcn_readfirstlane(irow[s]) & (TT - 1);
        const float* kr = k + ((size_t)(b * TT + kt)) * ROWS + tid * 8;
        float4 ka = *(const float4*)kr;
        float4 kb = *(const float4*)(kr + 4);
        float p = qa.x * ka.x + qa.y * ka.y + qa.z * ka.z + qa.w * ka.w
                + qb.x * kb.x + qb.y * kb.y + qb.z * kb.z + qb.w * kb.w;
        p += __shfl_xor(p, 1, 64);
        p += __shfl_xor(p, 2, 64);
        p += __shfl_xor(p, 4, 64);
        if ((l & 7) == 0) S[s][wave * 8 + h] = p;
    }
    __syncthreads();
    for (int j = tid; j < 8 * USAMP; j += 256) {
        int hh = j / USAMP, s = j - hh * USAMP;
        Dh[hh][s] = S[s][hh] + S[s][8 + hh] + S[s][16 + hh] + S[s][24 + hh];
    }
    __syncthreads();
    if (tid < 8) {
        float mx = -3.4e38f, sm = 0.f;
        #pragma unroll
        for (int s = 0; s < USAMP; ++s) {
            float d = Dh[tid][s];
            mx = fmaxf(mx, d);
            sm += d;
        }
        M[(((b << 3) + tid) << 9) + t] = mx - sm * (1.0f / TT);
    }
}

// exact top-k via rank + fused vmean final reduce. Grid: 32 x 512.
__global__ void topk_kernel(const float* __restrict__ M,
                            int* __restrict__ Mtop,
                            const float* __restrict__ vpart,
                            float* __restrict__ vmean, int U) {
    __shared__ float sM[TT];
    int bh = blockIdx.x;
    int t = threadIdx.x;
    sM[t] = M[bh * TT + t];
    if (t < 64) Mtop[bh * 64 + t] = 0;
    if (t < EE) {
        float acc = 0.f;
        #pragma unroll
        for (int c = 0; c < 8; ++c)
            acc += vpart[(bh * 8 + c) * EE + t];
        vmean[bh * EE + t] = acc * (1.0f / TT);
    }
    __syncthreads();
    float mv = sM[t];
    int rank = 0;
    for (int i = 0; i < TT; ++i) {
        float o = sM[i];
        rank += (o > mv) || (o == mv && i < t);
    }
    if (rank < U) Mtop[bh * 64 + rank] = t;
}

// Fused flash-chunked attention + vmean broadcast fill.
// R10 proven shape (CH=64/NCH=8, 256 attn blocks, 62.9 KB LDS) with staging
// vectorized to float4 (global dwordx4 + LDS b128, thread = row-group x e4).
// QK: 192-thread 3u x 4t strided tiles (conflict-free, R9-proven).
// PV: register-lean R8 form (no spill, R10-proven).
// Blocks 0..255: attn. Blocks 256..767: fill out with vmean.
__global__ __launch_bounds__(256)
void attn_fill(const float* __restrict__ q, const float* __restrict__ k,
               const float* __restrict__ v, const int* __restrict__ Mtop,
               const float* __restrict__ vmean, float* __restrict__ out,
               float* __restrict__ Opart, float* __restrict__ ml, int U) {
    __shared__ float qs[UPAD * 132];
    __shared__ float Bs[CH * 132];
    __shared__ float S[UPAD * 68];

    if (blockIdx.x >= 256) {
        int fb = blockIdx.x - 256;
        size_t i0 = (size_t)fb * 256 + threadIdx.x;
        #pragma unroll
        for (int r = 0; r < 8; ++r) {
            size_t tid4 = (i0 + (size_t)r * 131072) << 2;
            int d = tid4 & 63;
            size_t rest = tid4 >> 6;
            int h = rest & 7;  rest >>= 3;
            int nn = rest & 3; rest >>= 2;
            int b = (int)(rest >> 9);
            int e = (nn << 6) + d;
            int bh = (b << 3) + h;
            float4 val = *(const float4*)(vmean + (size_t)bh * EE + e);
            *(float4*)(out + tid4) = val;
        }
        return;
    }

    int bx = blockIdx.x;
    int bh = bx >> 3, ch = bx & 7;
    int b = bh >> 3, h = bh & 7;
    int tid = threadIdx.x;

    float acc[3][4];
    #pragma unroll
    for (int i = 0; i < 3; ++i)
        #pragma unroll
        for (int j = 0; j < 4; ++j) acc[i][j] = 0.f;

    int ug = tid >> 4, tg = tid & 15;   // QK: 12 ug x 16 tg = 192 active
    int e4s = tid & 31, r0s = tid >> 5; // staging: 32 e4-slots x 8 row-groups

    for (int h2 = 0; h2 < 2; ++h2) {
        int eb = h2 * 128;
        // ---- stage Q half: 36 rows x 32 float4 ----
        {
            int e = eb + (e4s << 2);
            size_t coloff = (size_t)((e >> 6) * HH + h) * DD + (e & 63);
            for (int u = r0s; u < UPAD; u += 8) {
                int uu = (u < U) ? u : (U - 1);
                int qt = Mtop[bh * 64 + uu] & (TT - 1);
                *(float4*)&qs[u * 132 + (e4s << 2)] =
                    *(const float4*)(q + ((size_t)(b * TT + qt)) * ROWS + coloff);
            }
        }
        // ---- stage K half: 64 rows x 32 float4 ----
        {
            int e = eb + (e4s << 2);
            size_t coloff = (size_t)((e >> 6) * HH + h) * DD + (e & 63);
            #pragma unroll
            for (int it = 0; it < 8; ++it) {
                int r = r0s + (it << 3);
                *(float4*)&Bs[r * 132 + (e4s << 2)] =
                    *(const float4*)(k + ((size_t)(b * TT + ch * CH + r)) * ROWS + coloff);
            }
        }
        __syncthreads();
        if (tid < 192) {
            const float4* Qv = (const float4*)qs;
            const float4* Bv = (const float4*)Bs;
            int u0 = ug * 3;
            for (int e4 = 0; e4 < 32; ++e4) {
                float4 k0 = Bv[(tg +  0) * 33 + e4];
                float4 k1 = Bv[(tg + 16) * 33 + e4];
                float4 k2 = Bv[(tg + 32) * 33 + e4];
                float4 k3 = Bv[(tg + 48) * 33 + e4];
                #pragma unroll
                for (int i = 0; i < 3; ++i) {
                    float4 qv = Qv[(u0 + i) * 33 + e4];
                    acc[i][0] += qv.x * k0.x + qv.y * k0.y + qv.z * k0.z + qv.w * k0.w;
                    acc[i][1] += qv.x * k1.x + qv.y * k1.y + qv.z * k1.z + qv.w * k1.w;
                    acc[i][2] += qv.x * k2.x + qv.y * k2.y + qv.z * k2.z + qv.w * k2.w;
                    acc[i][3] += qv.x * k3.x + qv.y * k3.y + qv.z * k3.z + qv.w * k3.w;
                }
            }
        }
        __syncthreads();
    }
    if (tid < 192) {
        int u0 = ug * 3;
        #pragma unroll
        for (int i = 0; i < 3; ++i)
            #pragma unroll
            for (int j = 0; j < 4; ++j)
                S[(u0 + i) * 68 + tg + 16 * j] = acc[i][j] * 0.125f;
    }
    __syncthreads();

    if (tid < UPAD) {
        float m = -3.4e38f;
        for (int t = 0; t < CH; ++t) m = fmaxf(m, S[tid * 68 + t]);
        float lsum = 0.f;
        for (int t = 0; t < CH; ++t) {
            float p = __expf(S[tid * 68 + t] - m);
            S[tid * 68 + t] = p;
            lsum += p;
        }
        size_t mli = ((size_t)(bh * NCH + ch) * UPAD + tid) * 2;
        ml[mli] = m;
        ml[mli + 1] = lsum;
    }
    __syncthreads();

    int ugp = tid >> 5, el = tid & 31;
    int u0p = ugp * 5;
    for (int vh = 0; vh < 2; ++vh) {
        // ---- stage V half: 64 rows x 32 float4 ----
        {
            int e = vh * 128 + (e4s << 2);
            size_t coloff = (size_t)((e >> 6) * HH + h) * DD + (e & 63);
            #pragma unroll
            for (int it = 0; it < 8; ++it) {
                int r = r0s + (it << 3);
                *(float4*)&Bs[r * 132 + (e4s << 2)] =
                    *(const float4*)(v + ((size_t)(b * TT + ch * CH + r)) * ROWS + coloff);
            }
        }
        __syncthreads();
        float4 o[5];
        #pragma unroll
        for (int i = 0; i < 5; ++i) o[i] = make_float4(0.f, 0.f, 0.f, 0.f);
        for (int t = 0; t < CH; ++t) {
            float4 v4 = *(const float4*)&Bs[t * 132 + 4 * el];
            #pragma unroll
            for (int i = 0; i < 5; ++i) {
                int uc = u0p + i; if (uc > 35) uc = 35;
                float p = S[uc * 68 + t];
                o[i].x += p * v4.x; o[i].y += p * v4.y;
                o[i].z += p * v4.z; o[i].w += p * v4.w;
            }
        }
        #pragma unroll
        for (int i = 0; i < 5; ++i) {
            int u = u0p + i;
            if (u < UPAD)
                *(float4*)&Opart[((size_t)(bh * NCH + ch) * UPAD + u) * EE + vh * 128 + 4 * el] = o[i];
        }
        __syncthreads();
    }
}

// merge chunk partials, write selected rows into out. Grid: 32*U x 64.
__global__ void combine_kernel(const float* __restrict__ Opart,
                               const float* __restrict__ ml,
                               const int* __restrict__ Mtop,
                               float* __restrict__ out, int U) {
    int bx = blockIdx.x;
    int bh = bx / U, ui = bx % U;
    int b = bh >> 3, h = bh & 7;
    int el = threadIdx.x;
    float mc[NCH], lc[NCH];
    float gm = -3.4e38f;
    #pragma unroll
    for (int c = 0; c < NCH; ++c) {
        size_t mli = ((size_t)(bh * NCH + c) * UPAD + ui) * 2;
        mc[c] = ml[mli]; lc[c] = ml[mli + 1];
        gm = fmaxf(gm, mc[c]);
    }
    float L = 0.f;
    float fc[NCH];
    #pragma unroll
    for (int c = 0; c < NCH; ++c) { fc[c] = __expf(mc[c] - gm); L += lc[c] * fc[c]; }
    float inv = 1.0f / L;
    float4 a = make_float4(0.f, 0.f, 0.f, 0.f);
    #pragma unroll
    for (int c = 0; c < NCH; ++c) {
        float4 o = *(const float4*)&Opart[((size_t)(bh * NCH + c) * UPAD + ui) * EE + 4 * el];
        a.x += fc[c] * o.x; a.y += fc[c] * o.y;
        a.z += fc[c] * o.z; a.w += fc[c] * o.w;
    }
    int qt = Mtop[bh * 64 + ui] & (TT - 1);
    int e0 = 4 * el, n = el >> 4;
    size_t ooff = ((size_t)(b * TT + qt)) * ROWS + (size_t)(n * HH + h) * DD + (e0 & 63);
    a.x *= inv; a.y *= inv; a.z *= inv; a.w *= inv;
    *(float4*)(out + ooff) = a;
}

// ---------------- mid-path kernels (ws >= 160 KB only) ----------------

__global__ __launch_bounds__(1024)
void vmean_kernel(const float* __restrict__ v, float* __restrict__ vmean) {
    __shared__ float part[4][EE];
    int bh = blockIdx.x;
    int b = bh >> 3, h = bh & 7;
    int e = threadIdx.x & 255;
    int chunk = threadIdx.x >> 8;
    int n = e >> 6, d = e & 63;
    size_t base = (size_t)b * TT * ROWS + (size_t)(n * HH + h) * DD + d;
    float acc = 0.f;
    int t0 = chunk * 128;
    for (int t = t0; t < t0 + 128; ++t)
        acc += v[base + (size_t)t * ROWS];
    part[chunk][e] = acc;
    __syncthreads();
    if (threadIdx.x < EE)
        vmean[bh * EE + threadIdx.x] =
            (part[0][threadIdx.x] + part[1][threadIdx.x] +
             part[2][threadIdx.x] + part[3][threadIdx.x]) * (1.0f / TT);
}

__global__ void fill_kernel(const float* __restrict__ vmean,
                            float* __restrict__ out) {
    size_t tid4 = ((size_t)blockIdx.x * 256 + threadIdx.x) << 2;
    int d = tid4 & 63;
    size_t rest = tid4 >> 6;
    int h = rest & 7;  rest >>= 3;
    int n = rest & 3;  rest >>= 2;
    int b = (int)(rest >> 9);
    int e = (n << 6) + d;
    int bh = (b << 3) + h;
    float4 val = *(const float4*)(vmean + (size_t)bh * EE + e);
    *(float4*)(out + tid4) = val;
}

__global__ void m_only_kernel(const float* __restrict__ q,
                              const float* __restrict__ k,
                              const int* __restrict__ idx,
                              float* __restrict__ M, int U) {
    int wave = threadIdx.x >> 6, lane = threadIdx.x & 63;
    int r = (blockIdx.x << 2) + wave;
    int t = r & (TT - 1);
    int bh = r >> 9;
    int b = bh >> 3, h = bh & 7;
    int g = lane >> 4, x = lane & 15;
    int n = x >> 2;
    int dbase = (x & 3) << 4;
    size_t colbase = (size_t)(n * HH + h) * DD + dbase;
    size_t qrow = ((size_t)(b * TT + t)) * ROWS + colbase;
    float4 qv0 = *(const float4*)(q + qrow);
    float4 qv1 = *(const float4*)(q + qrow + 4);
    float4 qv2 = *(const float4*)(q + qrow + 8);
    float4 qv3 = *(const float4*)(q + qrow + 12);
    float mx = -3.4e38f, sm = 0.f;
    int NB = (U + 3) >> 2;
    for (int bs = 0; bs < NB; ++bs) {
        int s = (bs << 2) + g;
        int valid = s < U;
        int sc = valid ? s : (U - 1);
        int kt = idx[t * U + sc] & (TT - 1);
        size_t krow = ((size_t)(b * TT + kt)) * ROWS + colbase;
        float4 kv0 = *(const float4*)(k + krow);
        float4 kv1 = *(const float4*)(k + krow + 4);
        float4 kv2 = *(const float4*)(k + krow + 8);
        float4 kv3 = *(const float4*)(k + krow + 12);
        float dot = qv0.x * kv0.x + qv0.y * kv0.y + qv0.z * kv0.z + qv0.w * kv0.w
                  + qv1.x * kv1.x + qv1.y * kv1.y + qv1.z * kv1.z + qv1.w * kv1.w
                  + qv2.x * kv2.x + qv2.y * kv2.y + qv2.z * kv2.z + qv2.w * kv2.w
                  + qv3.x * kv3.x + qv3.y * kv3.y + qv3.z * kv3.z + qv3.w * kv3.w;
        #pragma unroll
        for (int off = 1; off < 16; off <<= 1)
            dot += __shfl_xor(dot, off, 64);
        if (valid) { mx = fmaxf(mx, dot); sm += dot; }
    }
    mx = fmaxf(mx, __shfl_xor(mx, 16, 64));
    mx = fmaxf(mx, __shfl_xor(mx, 32, 64));
    sm += __shfl_xor(sm, 16, 64);
    sm += __shfl_xor(sm, 32, 64);
    if (lane == 0) M[r] = mx - sm * (1.0f / TT);
}

__global__ void topk_only_kernel(const float* __restrict__ M,
                                 int* __restrict__ Mtop, int U) {
    __shared__ float sM[TT];
    int bh = blockIdx.x;
    int t = threadIdx.x;
    sM[t] = M[bh * TT + t];
    if (t < 64) Mtop[bh * 64 + t] = 0;
    __syncthreads();
    float mv = sM[t];
    int rank = 0;
    for (int i = 0; i < TT; ++i) {
        float o = sM[i];
        rank += (o > mv) || (o == mv && i < t);
    }
    if (rank < U) Mtop[bh * 64 + rank] = t;
}

__global__ void update_kernel(const float* __restrict__ q,
                              const float* __restrict__ k,
                              const float* __restrict__ v,
                              const int* __restrict__ Mtop,
                              float* __restrict__ out, int U) {
    __shared__ float qs[EE];
    __shared__ float sc[TT];
    __shared__ float red[256];
    int blk = blockIdx.x;
    int ui = blk % U;
    int bh = blk / U;
    int b = bh >> 3, h = bh & 7;
    int tid = threadIdx.x;
    int qt = Mtop[bh * 64 + ui] & (TT - 1);
    {
        int n = tid >> 6, d = tid & 63;
        qs[tid] = q[((size_t)(b * TT + qt)) * ROWS + (size_t)(n * HH + h) * DD + d];
    }
    __syncthreads();
    #pragma unroll
    for (int rep = 0; rep < 2; ++rep) {
        int t = tid + rep * 256;
        size_t kb = ((size_t)(b * TT + t)) * ROWS + (size_t)h * DD;
        float acc = 0.f;
        #pragma unroll
        for (int n = 0; n < NN; ++n) {
            const float* kn = k + kb + (size_t)n * HH * DD;
            #pragma unroll 4
            for (int d4 = 0; d4 < DD; d4 += 4) {
                float4 kv = *(const float4*)(kn + d4);
                int e = n * 64 + d4;
                acc += qs[e] * kv.x + qs[e + 1] * kv.y + qs[e + 2] * kv.z + qs[e + 3] * kv.w;
            }
        }
        sc[t] = acc * 0.125f;
    }
    __syncthreads();
    red[tid] = fmaxf(sc[tid], sc[tid + 256]);
    __syncthreads();
    for (int s = 128; s > 0; s >>= 1) {
        if (tid < s) red[tid] = fmaxf(red[tid], red[tid + s]);
        __syncthreads();
    }
    float mx = red[0];
    __syncthreads();
    float e0 = __expf(sc[tid] - mx);
    float e1 = __expf(sc[tid + 256] - mx);
    sc[tid] = e0; sc[tid + 256] = e1;
    red[tid] = e0 + e1;
    __syncthreads();
    for (int s = 128; s > 0; s >>= 1) {
        if (tid < s) red[tid] += red[tid + s];
        __syncthreads();
    }
    float inv = 1.0f / red[0];
    __syncthreads();
    {
        int n = tid >> 6, d = tid & 63;
        size_t vb = (size_t)b * TT * ROWS + (size_t)(n * HH + h) * DD + d;
        float acc = 0.f;
        for (int t = 0; t < TT; ++t)
            acc += sc[t] * v[vb + (size_t)t * ROWS];
        out[((size_t)(b * TT + qt)) * ROWS + (size_t)(n * HH + h) * DD + d] = acc * inv;
    }
}

// ---------------- last-resort fallback (no ws): fused, fp32 ----------------
__global__ __launch_bounds__(1024)
void fused_probattn(const float* __restrict__ qp, const float* __restrict__ kp,
                    const float* __restrict__ vp, const int* __restrict__ idx,
                    float* __restrict__ out, int U) {
    __shared__ float vmean[EE];
    __shared__ float M[TT];
    __shared__ float sc[TT];
    __shared__ float qs[EE];
    __shared__ float red[64];
    __shared__ int   Mtop[64];
    const int bh = blockIdx.x;
    const int b = bh >> 3, h = bh & 7;
    const int tid = threadIdx.x;
    const int wave = tid >> 6, lane = tid & 63;
    if (tid < EE) {
        int n = tid >> 6, d = tid & 63;
        size_t base = (size_t)b * TT * ROWS + (size_t)(n * HH + h) * DD + d;
        float acc = 0.f;
        for (int t = 0; t < TT; ++t) acc += vp[base + (size_t)t * ROWS];
        vmean[tid] = acc * (1.0f / TT);
    }
    __syncthreads();
    for (int i = tid; i < TT * EE; i += 1024) {
        int t = i >> 8, e = i & 255;
        int n = e >> 6, d = e & 63;
        out[((size_t)(b * TT + t)) * ROWS + (size_t)(n * HH + h) * DD + d] = vmean[e];
    }
    {
        int e = lane << 2;
        int n = e >> 6, d = e & 63;
        size_t ebase = (size_t)(n * HH + h) * DD + d;
        for (int t = wave; t < TT; t += 16) {
            float4 qv = *(const float4*)(qp + ((size_t)(b * TT + t)) * ROWS + ebase);
            float mx = -3.4e38f, sm = 0.f;
            for (int s = 0; s < U; ++s) {
                int kt = idx[t * U + s] & (TT - 1);
                float4 kv = *(const float4*)(kp + ((size_t)(b * TT + kt)) * ROWS + ebase);
                float dot = qv.x * kv.x + qv.y * kv.y + qv.z * kv.z + qv.w * kv.w;
                #pragma unroll
                for (int off = 32; off; off >>= 1) dot += __shfl_xor(dot, off, 64);
                mx = fmaxf(mx, dot);
                sm += dot;
            }
            if (lane == 0) M[t] = mx - sm * (1.0f / TT);
        }
    }
    __syncthreads();
    if (tid < 64) Mtop[tid] = 0;
    __syncthreads();
    if (tid < TT) {
        float mv = M[tid];
        int rank = 0;
        for (int i = 0; i < TT; ++i) {
            float o = M[i];
            rank += (o > mv) || (o == mv && i < tid);
        }
        if (rank < U) Mtop[rank] = tid;
    }
    __syncthreads();
    for (int ui = 0; ui < U; ++ui) {
        int qt = Mtop[ui];
        if (tid < EE) {
            int n = tid >> 6, d = tid & 63;
            qs[tid] = qp[((size_t)(b * TT + qt)) * ROWS + (size_t)(n * HH + h) * DD + d];
        }
        __syncthreads();
        if (tid < TT) {
            float acc = 0.f;
            size_t kb = ((size_t)(b * TT + tid)) * ROWS + (size_t)h * DD;
            for (int n = 0; n < NN; ++n) {
                const float* kn = kp + kb + (size_t)n * HH * DD;
                for (int d = 0; d < DD; ++d) acc += qs[n * 64 + d] * kn[d];
            }
            sc[tid] = acc * 0.125f;
        }
        __syncthreads();
        float val = (tid < TT) ? sc[tid] : -3.4e38f;
        #pragma unroll
        for (int off = 32; off; off >>= 1) val = fmaxf(val, __shfl_xor(val, off, 64));
        if (lane == 0) red[wave] = val;
        __syncthreads();
        if (tid == 0) {
            float m = red[0];
            for (int w = 1; w < 16; ++w) m = fmaxf(m, red[w]);
            red[32] = m;
        }
        __syncthreads();
        float mx = red[32];
        float ev = 0.f;
        if (tid < TT) { ev = __expf(sc[tid] - mx); sc[tid] = ev; }
        __syncthreads();
        float sv = ev;
        #pragma unroll
        for (int off = 32; off; off >>= 1) sv += __shfl_xor(sv, off, 64);
        if (lane == 0) red[wave] = sv;
        __syncthreads();
        if (tid == 0) {
            float s = 0.f;
            for (int w = 0; w < 16; ++w) s += red[w];
            red[32] = s;
        }
        __syncthreads();
        float inv = 1.0f / red[32];
        if (tid < EE) {
            int n = tid >> 6, d = tid & 63;
            size_t vb = (size_t)b * TT * ROWS + (size_t)(n * HH + h) * DD + d;
            float acc = 0.f;
            for (int t = 0; t < TT; ++t) acc += sc[t] * vp[vb + (size_t)t * ROWS];
            out[((size_t)(b * TT + qt)) * ROWS + (size_t)(n * HH + h) * DD + d] = acc * inv;
        }
        __syncthreads();
    }
}

extern "C" void kernel_launch(void* const* d_in, const int* in_sizes, int n_in,
                              void* d_out, int out_size, void* d_ws, size_t ws_size,
                              hipStream_t stream) {
    const float* q = (const float*)d_in[0];
    const float* k = (const float*)d_in[1];
    const float* v = (const float*)d_in[2];
    const int* idx = (const int*)d_in[3];
    float* out = (float*)d_out;
    int U = in_sizes[3] / TT;        // 35

    // ws layout (bytes) — identical to R10:
    //   M      @ 0        (64 KB)
    //   Mtop   @ 65536    (8 KB)
    //   vmean  @ 98304    (32 KB)
    //   ml     @ 131072   (73.7 KB)  [flash only]
    //   Opart  @ 204800   (9.44 MB)  [flash only]
    //   vpart  @ 204800   (256 KB)   [flash only; aliases Opart — disjoint lifetime]
    const size_t NEED_FLASH = 204800 + (size_t)32 * NCH * UPAD * EE * 4 + 1024;
    const size_t NEED_MID = 160 * 1024;
    char* ws = (char*)d_ws;
    float* M     = (float*)(ws);
    int*   Mtop  = (int*)  (ws + 65536);
    float* vmean = (float*)(ws + 98304);
    float* ml    = (float*)(ws + 131072);
    float* Opart = (float*)(ws + 204800);
    float* vpart = (float*)(ws + 204800);

    if (ws_size >= NEED_FLASH && U == USAMP) {
        m2_kernel<<<2048 + 256, 256, 0, stream>>>(q, k, v, idx, M, vpart);
        topk_kernel<<<BB * HH, TT, 0, stream>>>(M, Mtop, vpart, vmean, U);
        attn_fill<<<256 + 512, 256, 0, stream>>>(q, k, v, Mtop, vmean, out, Opart, ml, U);
        combine_kernel<<<BB * HH * U, 64, 0, stream>>>(Opart, ml, Mtop, out, U);
    } else if (ws_size >= NEED_MID) {
        vmean_kernel<<<BB * HH, 1024, 0, stream>>>(v, vmean);
        fill_kernel<<<4096, 256, 0, stream>>>(vmean, out);
        m_only_kernel<<<BB * HH * TT / 4, 256, 0, stream>>>(q, k, idx, M, U);
        topk_only_kernel<<<BB * HH, TT, 0, stream>>>(M, Mtop, U);
        update_kernel<<<BB * HH * U, 256, 0, stream>>>(q, k, v, Mtop, out, U);
    } else {
        fused_probattn<<<BB * HH, 1024, 0, stream>>>(q, k, v, idx, out, U);
    }
}